// Round 16
// baseline (219.007 us; speedup 1.0000x reference)
//
#include <hip/hip_runtime.h>

#define NSND   49152
#define NRECV  115200
#define NSROWS (2 * NSND)     // 98304 dense sender rows (both batches)
#define NRROWS (2 * NRECV)    // 230400 receiver rows

typedef __bf16 bx8 __attribute__((ext_vector_type(8)));
typedef float  fx4 __attribute__((ext_vector_type(4)));

__device__ __forceinline__ unsigned short f2bf(float f) {
  unsigned u = __float_as_uint(f);
  u += 0x7FFFu + ((u >> 16) & 1u);   // round-to-nearest-even
  return (unsigned short)(u >> 16);
}

// ---------- prep 1: c1[n] = b1f[n] + sum_i ef_sum[i] * w1f[256+i][n] ----------
__global__ void prep_c1(const float* __restrict__ w1e, const float* __restrict__ b1e,
                        const float* __restrict__ w2e, const float* __restrict__ b2e,
                        const float* __restrict__ w1f, const float* __restrict__ b1f,
                        float* __restrict__ c1) {
  __shared__ float s_sum[64];
  __shared__ float s_ef[64];
  int t = threadIdx.x;
  if (t < 64) {
    float w = w1e[t], b = b1e[t];
    float acc = 0.f;
    for (int k = 0; k < 4; ++k) {
      float v = (float)k * w + b;
      acc += v / (1.f + expf(-v));      // silu over the 4 edge-attr values
    }
    s_sum[t] = acc;
  }
  __syncthreads();
  if (t < 64) {
    float acc = 4.f * b2e[t];
    for (int j = 0; j < 64; ++j) acc += s_sum[j] * w2e[j * 64 + t];
    s_ef[t] = acc;
  }
  __syncthreads();
  if (t < 256) {
    float acc = b1f[t];
    for (int i = 0; i < 64; ++i) acc += s_ef[i] * w1f[(256 + i) * 256 + t];
    c1[t] = acc;
  }
}

// ---------- prep 2: weights -> bf16, MFMA-fragment-contiguous layout ----------
// frag[ct(16)][ks(8)][lane(64)][8 bf16]; element = W[k][n], n=ct*16+(lane&15),
// k = ks*32 + (lane>>4)*8 + j.  A/B fragment lane layouts are symmetric, so this
// buffer serves as either operand (used as A in the transposed GEMMs).
__global__ void prep_w(const float* __restrict__ w1f, const float* __restrict__ w2f,
                       unsigned short* __restrict__ W1f, unsigned short* __restrict__ W2f) {
  int idx  = blockIdx.x * blockDim.x + threadIdx.x;   // 0..8191
  int lane = idx & 63;
  int ks   = (idx >> 6) & 7;
  int ct   = idx >> 9;
  int n     = ct * 16 + (lane & 15);
  int kbase = ks * 32 + (lane >> 4) * 8;
  unsigned p1[4], p2[4];
#pragma unroll
  for (int h = 0; h < 4; ++h) {
    int k = kbase + 2 * h;
    p1[h] = (unsigned)f2bf(w1f[k * 256 + n]) | ((unsigned)f2bf(w1f[(k + 1) * 256 + n]) << 16);
    p2[h] = (unsigned)f2bf(w2f[k * 256 + n]) | ((unsigned)f2bf(w2f[(k + 1) * 256 + n]) << 16);
  }
  *(uint4*)(W1f + (size_t)idx * 8) = make_uint4(p1[0], p1[1], p1[2], p1[3]);
  *(uint4*)(W2f + (size_t)idx * 8) = make_uint4(p2[0], p2[1], p2[2], p2[3]);
}

// ---------- K1: Y' = x @ W1 + c1/4, W1-in-LDS (R12-validated, ~roofline) ----------
__global__ __launch_bounds__(512, 2) void k1_senders(
    const float* __restrict__ x, const float* __restrict__ c1,
    const unsigned short* __restrict__ W1f, unsigned short* __restrict__ Yp) {
  __shared__ char lds[65536];              // 64 KiB

  const int lane = threadIdx.x & 63;
  const int wv   = threadIdx.x >> 6;       // 0..7
  const int row  = lane & 15;
  const int kg   = lane >> 4;              // 0..3
  const int rb   = blockIdx.x * 128;       // sender row base of block

  const float* xr = x + (size_t)(rb + wv * 16 + row) * 256;
  bx8 hfr[8];
#pragma unroll
  for (int ks = 0; ks < 8; ++ks) {
    fx4 a = __builtin_nontemporal_load((const fx4*)(xr + ks * 32 + kg * 8));
    fx4 c = __builtin_nontemporal_load((const fx4*)(xr + ks * 32 + kg * 8 + 4));
    unsigned p0 = (unsigned)f2bf(a.x) | ((unsigned)f2bf(a.y) << 16);
    unsigned p1 = (unsigned)f2bf(a.z) | ((unsigned)f2bf(a.w) << 16);
    unsigned p2 = (unsigned)f2bf(c.x) | ((unsigned)f2bf(c.y) << 16);
    unsigned p3 = (unsigned)f2bf(c.z) | ((unsigned)f2bf(c.w) << 16);
    uint4 pu = make_uint4(p0, p1, p2, p3);
    hfr[ks] = *(bx8*)&pu;
  }

  fx4 acc[16];
#pragma unroll
  for (int nc = 0; nc < 16; ++nc) acc[nc] = (fx4){0.f, 0.f, 0.f, 0.f};

#pragma unroll
  for (int i = 0; i < 8; ++i) {
    unsigned off = (unsigned)(wv * 8192 + i * 1024 + lane * 16);
    *(uint4*)(lds + off) = *(const uint4*)((const char*)W1f + off);
  }
  __syncthreads();
#pragma unroll
  for (int ks = 0; ks < 8; ++ks) {
#pragma unroll
    for (int q = 0; q < 8; ++q) {
      bx8 wfr = *(const bx8*)(lds + (unsigned)((q * 8 + ks) * 1024 + lane * 16));
      acc[q] = __builtin_amdgcn_mfma_f32_16x16x32_bf16(wfr, hfr[ks], acc[q], 0, 0, 0);
    }
  }
  __syncthreads();

#pragma unroll
  for (int i = 0; i < 8; ++i) {
    unsigned off = (unsigned)(wv * 8192 + i * 1024 + lane * 16);
    *(uint4*)(lds + off) = *(const uint4*)((const char*)W1f + 65536 + off);
  }
  __syncthreads();
#pragma unroll
  for (int ks = 0; ks < 8; ++ks) {
#pragma unroll
    for (int q = 0; q < 8; ++q) {
      bx8 wfr = *(const bx8*)(lds + (unsigned)((q * 8 + ks) * 1024 + lane * 16));
      acc[8 + q] = __builtin_amdgcn_mfma_f32_16x16x32_bf16(wfr, hfr[ks], acc[8 + q], 0, 0, 0);
    }
  }
  __syncthreads();   // all W1 reads done before epilogue reuses LDS

  const fx4* c1_4 = (const fx4*)c1;
#pragma unroll
  for (int nc = 0; nc < 16; ++nc) {
    fx4 cv = c1_4[nc * 4 + kg];
    unsigned lo = (unsigned)f2bf(acc[nc][0] + 0.25f * cv.x)
                | ((unsigned)f2bf(acc[nc][1] + 0.25f * cv.y) << 16);
    unsigned hi = (unsigned)f2bf(acc[nc][2] + 0.25f * cv.z)
                | ((unsigned)f2bf(acc[nc][3] + 0.25f * cv.w) << 16);
    unsigned sb = (unsigned)(wv * 8192 + row * 512 + nc * 32 + kg * 8)
                ^ (unsigned)((row & 7) << 4);
    *(uint2*)(lds + sb) = make_uint2(lo, hi);
  }
#pragma unroll
  for (int i = 0; i < 8; ++i) {
    int srow  = 2 * i + (lane >> 5);
    int chunk = lane & 31;
    unsigned sb = (unsigned)(wv * 8192 + srow * 512 + chunk * 16)
                ^ (unsigned)((srow & 7) << 4);
    uint4 v = *(const uint4*)(lds + sb);
    *(uint4*)(Yp + (size_t)(rb + wv * 16 + srow) * 256 + chunk * 8) = v;
  }
}

// ---------- kA: gather-sum Y' -> silu -> H (pure streaming, no LDS/MFMA) ----------
// grid 2400, block 256. Task = one 16B chunk of one H row (230400 x 32 tasks,
// exactly 12 per thread). 4 tasks batched -> 16 loads in flight per lane,
// pinned by sched_barrier(0). Stores: lanes 0..31 = row r chunks 0..31 -> each
// wave store covers contiguous full lines. H kept in L3 for kB.
__global__ __launch_bounds__(256, 4) void kA_gather(
    const unsigned short* __restrict__ Yp, const int* __restrict__ edge_src,
    unsigned short* __restrict__ H) {
  const int tid0 = blockIdx.x * 256 + threadIdx.x;   // 0..614399
  const int4* esrc4 = (const int4*)edge_src;

#pragma unroll
  for (int it = 0; it < 3; ++it) {
    bx8 d[4][4];
    int rows[4], chunks[4];
#pragma unroll
    for (int j = 0; j < 4; ++j) {
      int task  = tid0 + (it * 4 + j) * 614400;      // < 7372800
      int row   = task >> 5;                         // global receiver row
      int chunk = task & 31;
      rows[j] = row; chunks[j] = chunk;
      int bb = row >= NRECV;
      int rr = row - bb * NRECV;
      int4 s = esrc4[rr];
      const unsigned short* yb = Yp + (size_t)bb * NSND * 256;
      d[j][0] = *(const bx8*)(yb + (size_t)s.x * 256 + chunk * 8);
      d[j][1] = *(const bx8*)(yb + (size_t)s.y * 256 + chunk * 8);
      d[j][2] = *(const bx8*)(yb + (size_t)s.z * 256 + chunk * 8);
      d[j][3] = *(const bx8*)(yb + (size_t)s.w * 256 + chunk * 8);
    }
    __builtin_amdgcn_sched_barrier(0);               // keep the 16 loads batched
#pragma unroll
    for (int j = 0; j < 4; ++j) {
      unsigned p[4];
#pragma unroll
      for (int h = 0; h < 4; ++h) {
        float v0 = (float)d[j][0][2*h] + (float)d[j][1][2*h] + (float)d[j][2][2*h] + (float)d[j][3][2*h];
        float v1 = (float)d[j][0][2*h+1] + (float)d[j][1][2*h+1] + (float)d[j][2][2*h+1] + (float)d[j][3][2*h+1];
        float h0 = v0 / (1.f + __expf(-v0));         // silu
        float h1 = v1 / (1.f + __expf(-v1));
        p[h] = (unsigned)f2bf(h0) | ((unsigned)f2bf(h1) << 16);
      }
      *(uint4*)(H + (size_t)rows[j] * 256 + chunks[j] * 8) = make_uint4(p[0], p[1], p[2], p[3]);
    }
  }
}

// ---------- kB: out = H @ W2 + b2f (dense, k1's validated roofline structure) ----------
// grid 1800, block 512 (8 waves, 16 rows/wave). W2 staged in two 64 KiB LDS
// halves, two MFMA passes; H fragments loaded reg-direct (plain bx8 loads);
// staged f32 epilogue with full-line nt stores.
__global__ __launch_bounds__(512, 2) void kB_dense(
    const unsigned short* __restrict__ H, const unsigned short* __restrict__ W2f,
    const float* __restrict__ b2f, float* __restrict__ out) {
  __shared__ char lds[65536];              // 64 KiB

  const int lane = threadIdx.x & 63;
  const int wv   = threadIdx.x >> 6;       // 0..7
  const int row  = lane & 15;
  const int kg   = lane >> 4;              // 0..3
  const int rb   = blockIdx.x * 128;       // global receiver row base

  // reg-direct H fragments: H[row][k], k = ks*32 + kg*8 + j (row-major, direct)
  const unsigned short* hr = H + (size_t)(rb + wv * 16 + row) * 256;
  bx8 hfr[8];
#pragma unroll
  for (int ks = 0; ks < 8; ++ks)
    hfr[ks] = *(const bx8*)(hr + ks * 32 + kg * 8);

  fx4 acc[16];
#pragma unroll
  for (int nc = 0; nc < 16; ++nc) acc[nc] = (fx4){0.f, 0.f, 0.f, 0.f};

  // stage W2 half 0 (nc 0-7), MFMA pass
#pragma unroll
  for (int i = 0; i < 8; ++i) {
    unsigned off = (unsigned)(wv * 8192 + i * 1024 + lane * 16);
    *(uint4*)(lds + off) = *(const uint4*)((const char*)W2f + off);
  }
  __syncthreads();
#pragma unroll
  for (int ks = 0; ks < 8; ++ks) {
#pragma unroll
    for (int q = 0; q < 8; ++q) {
      bx8 wfr = *(const bx8*)(lds + (unsigned)((q * 8 + ks) * 1024 + lane * 16));
      acc[q] = __builtin_amdgcn_mfma_f32_16x16x32_bf16(wfr, hfr[ks], acc[q], 0, 0, 0);
    }
  }
  __syncthreads();

  // stage W2 half 1 (nc 8-15), MFMA pass
#pragma unroll
  for (int i = 0; i < 8; ++i) {
    unsigned off = (unsigned)(wv * 8192 + i * 1024 + lane * 16);
    *(uint4*)(lds + off) = *(const uint4*)((const char*)W2f + 65536 + off);
  }
  __syncthreads();
#pragma unroll
  for (int ks = 0; ks < 8; ++ks) {
#pragma unroll
    for (int q = 0; q < 8; ++q) {
      bx8 wfr = *(const bx8*)(lds + (unsigned)((q * 8 + ks) * 1024 + lane * 16));
      acc[8 + q] = __builtin_amdgcn_mfma_f32_16x16x32_bf16(wfr, hfr[ks], acc[8 + q], 0, 0, 0);
    }
  }
  __syncthreads();   // all W2 reads complete before epilogue overwrites LDS

  // staged epilogue (R7/R13-validated): f32 in 8 KiB/wave LDS slice, then
  // full-line nt stores (each instr = contiguous aligned 1 KiB).
  const fx4* b2f4 = (const fx4*)b2f;
  const size_t orow0 = (size_t)(rb + wv * 16) * 256;
#pragma unroll
  for (int p = 0; p < 2; ++p) {
#pragma unroll
    for (int q = 0; q < 8; ++q) {
      int nc = p * 8 + q;
      fx4 o = acc[nc] + b2f4[nc * 4 + kg];
      unsigned sb = (unsigned)(wv * 8192 + row * 512 + q * 64 + kg * 16)
                  ^ (unsigned)((row & 7) << 4);
      *(fx4*)(lds + sb) = o;
    }
#pragma unroll
    for (int i = 0; i < 8; ++i) {
      int srow  = 2 * i + (lane >> 5);     // 0..15
      int chunk = lane & 31;               // 16B chunk within 512B
      unsigned sb = (unsigned)(wv * 8192 + srow * 512 + chunk * 16)
                  ^ (unsigned)((srow & 7) << 4);
      fx4 v = *(const fx4*)(lds + sb);
      __builtin_nontemporal_store(v, (fx4*)(out + orow0 + (size_t)srow * 256 + p * 128 + chunk * 4));
    }
  }
}

// ---------- K23 fused (R15-validated, 139 us) — fallback if ws < need_big ----------
__global__ __launch_bounds__(512, 2) void k23_recv(
    const unsigned short* __restrict__ Yp, const int* __restrict__ edge_src,
    const unsigned short* __restrict__ W2f, const float* __restrict__ b2f,
    float* __restrict__ out) {
  __shared__ char lds[65536];              // 64 KiB

  const int tid  = threadIdx.x;
  const int lane = tid & 63;
  const int wv   = tid >> 6;               // 0..7
  const int row  = lane & 15;
  const int kg   = lane >> 4;

  const int blk = blockIdx.x;
  const int b   = blk / 900;
  const int rr0 = (blk % 900) * 128;
  const unsigned short* yb = Yp + (size_t)b * NSND * 256;

  int4 s = ((const int4*)edge_src)[rr0 + wv * 16 + row];
  const unsigned short* y0 = yb + (size_t)s.x * 256 + kg * 8;
  const unsigned short* y1 = yb + (size_t)s.y * 256 + kg * 8;
  const unsigned short* y2 = yb + (size_t)s.z * 256 + kg * 8;
  const unsigned short* y3 = yb + (size_t)s.w * 256 + kg * 8;

  bx8 hfr[8];
#pragma unroll
  for (int g = 0; g < 2; ++g) {
    bx8 d[4][4];
#pragma unroll
    for (int t = 0; t < 4; ++t) {
      int ks = g * 4 + t;
      d[t][0] = *(const bx8*)(y0 + ks * 32);
      d[t][1] = *(const bx8*)(y1 + ks * 32);
      d[t][2] = *(const bx8*)(y2 + ks * 32);
      d[t][3] = *(const bx8*)(y3 + ks * 32);
    }
    __builtin_amdgcn_sched_barrier(0);
#pragma unroll
    for (int t = 0; t < 4; ++t) {
      int ks = g * 4 + t;
      unsigned p[4];
#pragma unroll
      for (int h = 0; h < 4; ++h) {
        float v0 = (float)d[t][0][2*h] + (float)d[t][1][2*h] + (float)d[t][2][2*h] + (float)d[t][3][2*h];
        float v1 = (float)d[t][0][2*h+1] + (float)d[t][1][2*h+1] + (float)d[t][2][2*h+1] + (float)d[t][3][2*h+1];
        float h0 = v0 / (1.f + __expf(-v0));
        float h1 = v1 / (1.f + __expf(-v1));
        p[h] = (unsigned)f2bf(h0) | ((unsigned)f2bf(h1) << 16);
      }
      uint4 pu = make_uint4(p[0], p[1], p[2], p[3]);
      hfr[ks] = *(bx8*)&pu;
    }
  }

#pragma unroll
  for (int i = 0; i < 8; ++i) {
    unsigned off = (unsigned)(wv * 8192 + i * 1024 + lane * 16);
    uint4 v = *(const uint4*)((const char*)W2f + off);
    *(uint4*)(lds + off) = v;
  }
  __syncthreads();

  fx4 acc[16];
#pragma unroll
  for (int nc = 0; nc < 16; ++nc) acc[nc] = (fx4){0.f, 0.f, 0.f, 0.f};

#pragma unroll
  for (int ks = 0; ks < 8; ++ks) {
#pragma unroll
    for (int q = 0; q < 8; ++q) {
      bx8 wfr = *(const bx8*)(lds + (unsigned)((q * 8 + ks) * 1024 + lane * 16));
      acc[q] = __builtin_amdgcn_mfma_f32_16x16x32_bf16(wfr, hfr[ks], acc[q], 0, 0, 0);
    }
  }
  __syncthreads();

#pragma unroll
  for (int i = 0; i < 8; ++i) {
    unsigned off = (unsigned)(wv * 8192 + i * 1024 + lane * 16);
    uint4 v = *(const uint4*)((const char*)W2f + 65536 + off);
    *(uint4*)(lds + off) = v;
  }
  __syncthreads();

#pragma unroll
  for (int ks = 0; ks < 8; ++ks) {
#pragma unroll
    for (int q = 0; q < 8; ++q) {
      bx8 wfr = *(const bx8*)(lds + (unsigned)((q * 8 + ks) * 1024 + lane * 16));
      acc[8 + q] = __builtin_amdgcn_mfma_f32_16x16x32_bf16(wfr, hfr[ks], acc[8 + q], 0, 0, 0);
    }
  }
  __syncthreads();

  const fx4* b2f4 = (const fx4*)b2f;
  const size_t orow0 = ((size_t)b * NRECV + rr0 + wv * 16) * 256;
#pragma unroll
  for (int p = 0; p < 2; ++p) {
#pragma unroll
    for (int q = 0; q < 8; ++q) {
      int nc = p * 8 + q;
      fx4 o = acc[nc] + b2f4[nc * 4 + kg];
      unsigned sb = (unsigned)(wv * 8192 + row * 512 + q * 64 + kg * 16)
                  ^ (unsigned)((row & 7) << 4);
      *(fx4*)(lds + sb) = o;
    }
#pragma unroll
    for (int i = 0; i < 8; ++i) {
      int srow  = 2 * i + (lane >> 5);
      int chunk = lane & 31;
      unsigned sb = (unsigned)(wv * 8192 + srow * 512 + chunk * 16)
                  ^ (unsigned)((srow & 7) << 4);
      fx4 v = *(const fx4*)(lds + sb);
      __builtin_nontemporal_store(v, (fx4*)(out + orow0 + (size_t)srow * 256 + p * 128 + chunk * 4));
    }
  }
}

// ---------- fallback (R3-validated fused kernel) if ws is tiny ----------
__global__ __launch_bounds__(256, 4) void heal_fused(
    const float* __restrict__ x, const int* __restrict__ edge_src,
    const float* __restrict__ c1, const unsigned short* __restrict__ W1f,
    const unsigned short* __restrict__ W2f, const float* __restrict__ b2f,
    float* __restrict__ out) {
  __shared__ char lds[64 * 512];
  const int lane = threadIdx.x & 63;
  const int wv   = threadIdx.x >> 6;
  const int blk = blockIdx.x;
  const int b   = blk / 1800;
  const int r0  = (blk % 1800) * 64;
  const float* xb = x + (size_t)b * NSND * 256;
#pragma unroll 4
  for (int i = 0; i < 16; ++i) {
    int row = wv * 16 + i;
    int r   = r0 + row;
    int4 s  = *(const int4*)(edge_src + 4 * (size_t)r);
    float4 a0 = *((const float4*)(xb + (size_t)s.x * 256) + lane);
    float4 a1 = *((const float4*)(xb + (size_t)s.y * 256) + lane);
    float4 a2 = *((const float4*)(xb + (size_t)s.z * 256) + lane);
    float4 a3 = *((const float4*)(xb + (size_t)s.w * 256) + lane);
    float v0 = a0.x + a1.x + a2.x + a3.x;
    float v1 = a0.y + a1.y + a2.y + a3.y;
    float v2 = a0.z + a1.z + a2.z + a3.z;
    float v3 = a0.w + a1.w + a2.w + a3.w;
    unsigned lo = (unsigned)f2bf(v0) | ((unsigned)f2bf(v1) << 16);
    unsigned hi = (unsigned)f2bf(v2) | ((unsigned)f2bf(v3) << 16);
    unsigned byte = (unsigned)(row * 512 + lane * 8) ^ (unsigned)((row & 7) << 4);
    *(uint2*)(lds + byte) = make_uint2(lo, hi);
  }
  fx4 acc[16];
#pragma unroll
  for (int nc = 0; nc < 16; ++nc) acc[nc] = (fx4){0.f, 0.f, 0.f, 0.f};
  const bx8* W1v = (const bx8*)W1f;
  const int arow = wv * 16 + (lane & 15);
  const unsigned aswz = (unsigned)((arow & 7) << 4);
  const unsigned alin = (unsigned)(arow * 512 + (lane >> 4) * 16);
#pragma unroll
  for (int ks = 0; ks < 8; ++ks) {
    bx8 afr = *(const bx8*)(lds + ((alin + ks * 64) ^ aswz));
#pragma unroll
    for (int nc = 0; nc < 16; ++nc) {
      bx8 bfr = W1v[(nc * 8 + ks) * 64 + lane];
      acc[nc] = __builtin_amdgcn_mfma_f32_16x16x32_bf16(afr, bfr, acc[nc], 0, 0, 0);
    }
  }
  float c1v[16];
#pragma unroll
  for (int nc = 0; nc < 16; ++nc) c1v[nc] = c1[nc * 16 + (lane & 15)];
#pragma unroll
  for (int nc = 0; nc < 16; ++nc) {
    int hcol = nc * 16 + (lane & 15);
#pragma unroll
    for (int j = 0; j < 4; ++j) {
      float v = acc[nc][j] + c1v[nc];
      float h = v / (1.f + __expf(-v));
      int hrow = wv * 16 + (lane >> 4) * 4 + j;
      unsigned hb = (unsigned)(hrow * 512 + hcol * 2) ^ (unsigned)((hrow & 7) << 4);
      *(unsigned short*)(lds + hb) = f2bf(h);
    }
  }
#pragma unroll
  for (int nc = 0; nc < 16; ++nc) acc[nc] = (fx4){0.f, 0.f, 0.f, 0.f};
  const bx8* W2v = (const bx8*)W2f;
#pragma unroll
  for (int ks = 0; ks < 8; ++ks) {
    bx8 afr = *(const bx8*)(lds + ((alin + ks * 64) ^ aswz));
#pragma unroll
    for (int nc = 0; nc < 16; ++nc) {
      bx8 bfr = W2v[(nc * 8 + ks) * 64 + lane];
      acc[nc] = __builtin_amdgcn_mfma_f32_16x16x32_bf16(afr, bfr, acc[nc], 0, 0, 0);
    }
  }
  size_t obase = ((size_t)b * NRECV + r0) * 256;
#pragma unroll
  for (int nc = 0; nc < 16; ++nc) {
    int col = nc * 16 + (lane & 15);
    float bias = b2f[col];
#pragma unroll
    for (int j = 0; j < 4; ++j) {
      int row = wv * 16 + (lane >> 4) * 4 + j;
      out[obase + (size_t)row * 256 + col] = acc[nc][j] + bias;
    }
  }
}

extern "C" void kernel_launch(void* const* d_in, const int* in_sizes, int n_in,
                              void* d_out, int out_size, void* d_ws, size_t ws_size,
                              hipStream_t stream) {
  const float* x    = (const float*)d_in[0];
  const float* w1e  = (const float*)d_in[2];
  const float* b1e  = (const float*)d_in[3];
  const float* w2e  = (const float*)d_in[4];
  const float* b2e  = (const float*)d_in[5];
  const float* w1f  = (const float*)d_in[6];
  const float* b1f  = (const float*)d_in[7];
  const float* w2f  = (const float*)d_in[8];
  const float* b2f  = (const float*)d_in[9];
  const int* edge_src = (const int*)d_in[10];
  float* out = (float*)d_out;

  char* ws = (char*)d_ws;
  float* c1            = (float*)ws;                       // @0, 1 KiB
  unsigned short* W1f  = (unsigned short*)(ws + 4096);     // 128 KiB
  unsigned short* W2f  = (unsigned short*)(ws + 4096 + 131072);
  unsigned short* Yp   = (unsigned short*)(ws + 1048576);  // 48 MiB bf16 Y'
  unsigned short* H    = (unsigned short*)(ws + 1048576 + (size_t)NSROWS * 256 * 2);
  const size_t need_old = 1048576 + (size_t)NSROWS * 256 * 2;
  const size_t need_big = need_old + (size_t)NRROWS * 256 * 2;   // +112.5 MiB

  hipLaunchKernelGGL(prep_c1, dim3(1), dim3(256), 0, stream, w1e, b1e, w2e, b2e, w1f, b1f, c1);
  hipLaunchKernelGGL(prep_w, dim3(32), dim3(256), 0, stream, w1f, w2f, W1f, W2f);
  if (ws_size >= need_big) {
    hipLaunchKernelGGL(k1_senders, dim3(NSROWS / 128), dim3(512), 0, stream, x, c1, W1f, Yp);
    hipLaunchKernelGGL(kA_gather, dim3(2400), dim3(256), 0, stream, Yp, edge_src, H);
    hipLaunchKernelGGL(kB_dense, dim3(NRROWS / 128), dim3(512), 0, stream, H, W2f, b2f, out);
  } else if (ws_size >= need_old) {
    hipLaunchKernelGGL(k1_senders, dim3(NSROWS / 128), dim3(512), 0, stream, x, c1, W1f, Yp);
    hipLaunchKernelGGL(k23_recv, dim3(NRROWS / 128), dim3(512), 0, stream,
                       Yp, edge_src, W2f, b2f, out);
  } else {
    hipLaunchKernelGGL(heal_fused, dim3(NRROWS / 64), dim3(256), 0, stream,
                       x, edge_src, c1, W1f, W2f, b2f, out);
  }
}

// Round 17
// 162.674 us; speedup vs baseline: 1.3463x; 1.3463x over previous
//
#include <hip/hip_runtime.h>

#define NSND   49152
#define NRECV  115200
#define NSROWS (2 * NSND)     // 98304 dense sender rows (both batches)
#define NRROWS (2 * NRECV)    // 230400 receiver rows

typedef __bf16 bx8 __attribute__((ext_vector_type(8)));
typedef float  fx4 __attribute__((ext_vector_type(4)));

__device__ __forceinline__ unsigned short f2bf(float f) {
  unsigned u = __float_as_uint(f);
  u += 0x7FFFu + ((u >> 16) & 1u);   // round-to-nearest-even
  return (unsigned short)(u >> 16);
}

// ---------- prep 1: c1[n] = b1f[n] + sum_i ef_sum[i] * w1f[256+i][n] ----------
__global__ void prep_c1(const float* __restrict__ w1e, const float* __restrict__ b1e,
                        const float* __restrict__ w2e, const float* __restrict__ b2e,
                        const float* __restrict__ w1f, const float* __restrict__ b1f,
                        float* __restrict__ c1) {
  __shared__ float s_sum[64];
  __shared__ float s_ef[64];
  int t = threadIdx.x;
  if (t < 64) {
    float w = w1e[t], b = b1e[t];
    float acc = 0.f;
    for (int k = 0; k < 4; ++k) {
      float v = (float)k * w + b;
      acc += v / (1.f + expf(-v));      // silu over the 4 edge-attr values
    }
    s_sum[t] = acc;
  }
  __syncthreads();
  if (t < 64) {
    float acc = 4.f * b2e[t];
    for (int j = 0; j < 64; ++j) acc += s_sum[j] * w2e[j * 64 + t];
    s_ef[t] = acc;
  }
  __syncthreads();
  if (t < 256) {
    float acc = b1f[t];
    for (int i = 0; i < 64; ++i) acc += s_ef[i] * w1f[(256 + i) * 256 + t];
    c1[t] = acc;
  }
}

// ---------- prep 2: weights -> bf16, MFMA-fragment-contiguous layout ----------
// frag[ct(16)][ks(8)][lane(64)][8 bf16]; element = W[k][n], n=ct*16+(lane&15),
// k = ks*32 + (lane>>4)*8 + j.  A/B fragment lane layouts are symmetric, so this
// buffer serves as either operand (used as A in the transposed GEMMs).
__global__ void prep_w(const float* __restrict__ w1f, const float* __restrict__ w2f,
                       unsigned short* __restrict__ W1f, unsigned short* __restrict__ W2f) {
  int idx  = blockIdx.x * blockDim.x + threadIdx.x;   // 0..8191
  int lane = idx & 63;
  int ks   = (idx >> 6) & 7;
  int ct   = idx >> 9;
  int n     = ct * 16 + (lane & 15);
  int kbase = ks * 32 + (lane >> 4) * 8;
  unsigned p1[4], p2[4];
#pragma unroll
  for (int h = 0; h < 4; ++h) {
    int k = kbase + 2 * h;
    p1[h] = (unsigned)f2bf(w1f[k * 256 + n]) | ((unsigned)f2bf(w1f[(k + 1) * 256 + n]) << 16);
    p2[h] = (unsigned)f2bf(w2f[k * 256 + n]) | ((unsigned)f2bf(w2f[(k + 1) * 256 + n]) << 16);
  }
  *(uint4*)(W1f + (size_t)idx * 8) = make_uint4(p1[0], p1[1], p1[2], p1[3]);
  *(uint4*)(W2f + (size_t)idx * 8) = make_uint4(p2[0], p2[1], p2[2], p2[3]);
}

// ---------- K1: Y' = x @ W1 + c1/4, W1-in-LDS (R12-validated, ~roofline) ----------
// grid 768, block 512 (8 waves, 16 rows/wave = 128 rows/block). LDS 64 KiB:
// W1 staged in two halves (nc 0-7 / 8-15), two MFMA passes; x fragments loaded
// reg-direct (lane-local, dense); staged bf16 epilogue, full-row streams.
__global__ __launch_bounds__(512, 2) void k1_senders(
    const float* __restrict__ x, const float* __restrict__ c1,
    const unsigned short* __restrict__ W1f, unsigned short* __restrict__ Yp) {
  __shared__ char lds[65536];              // 64 KiB

  const int lane = threadIdx.x & 63;
  const int wv   = threadIdx.x >> 6;       // 0..7
  const int row  = lane & 15;
  const int kg   = lane >> 4;              // 0..3
  const int rb   = blockIdx.x * 128;       // sender row base of block

  // phase A: reg-direct x fragments (B-operand of transposed GEMM1):
  // x[row][k], k = ks*32 + kg*8 + j  -> 2 fx4 nt loads per ks, cvt to bf16x8
  const float* xr = x + (size_t)(rb + wv * 16 + row) * 256;
  bx8 hfr[8];
#pragma unroll
  for (int ks = 0; ks < 8; ++ks) {
    fx4 a = __builtin_nontemporal_load((const fx4*)(xr + ks * 32 + kg * 8));
    fx4 c = __builtin_nontemporal_load((const fx4*)(xr + ks * 32 + kg * 8 + 4));
    unsigned p0 = (unsigned)f2bf(a.x) | ((unsigned)f2bf(a.y) << 16);
    unsigned p1 = (unsigned)f2bf(a.z) | ((unsigned)f2bf(a.w) << 16);
    unsigned p2 = (unsigned)f2bf(c.x) | ((unsigned)f2bf(c.y) << 16);
    unsigned p3 = (unsigned)f2bf(c.z) | ((unsigned)f2bf(c.w) << 16);
    uint4 pu = make_uint4(p0, p1, p2, p3);
    hfr[ks] = *(bx8*)&pu;
  }

  fx4 acc[16];
#pragma unroll
  for (int nc = 0; nc < 16; ++nc) acc[nc] = (fx4){0.f, 0.f, 0.f, 0.f};

  // phase B0/C0: stage W1 half 0 (nc 0-7), MFMA pass
#pragma unroll
  for (int i = 0; i < 8; ++i) {
    unsigned off = (unsigned)(wv * 8192 + i * 1024 + lane * 16);
    *(uint4*)(lds + off) = *(const uint4*)((const char*)W1f + off);
  }
  __syncthreads();
#pragma unroll
  for (int ks = 0; ks < 8; ++ks) {
#pragma unroll
    for (int q = 0; q < 8; ++q) {
      bx8 wfr = *(const bx8*)(lds + (unsigned)((q * 8 + ks) * 1024 + lane * 16));
      acc[q] = __builtin_amdgcn_mfma_f32_16x16x32_bf16(wfr, hfr[ks], acc[q], 0, 0, 0);
    }
  }
  __syncthreads();

  // phase B1/C1: stage W1 half 1 (nc 8-15), MFMA pass
#pragma unroll
  for (int i = 0; i < 8; ++i) {
    unsigned off = (unsigned)(wv * 8192 + i * 1024 + lane * 16);
    *(uint4*)(lds + off) = *(const uint4*)((const char*)W1f + 65536 + off);
  }
  __syncthreads();
#pragma unroll
  for (int ks = 0; ks < 8; ++ks) {
#pragma unroll
    for (int q = 0; q < 8; ++q) {
      bx8 wfr = *(const bx8*)(lds + (unsigned)((q * 8 + ks) * 1024 + lane * 16));
      acc[8 + q] = __builtin_amdgcn_mfma_f32_16x16x32_bf16(wfr, hfr[ks], acc[8 + q], 0, 0, 0);
    }
  }
  __syncthreads();   // all W1 reads done before epilogue reuses LDS

  // phase D: Y'[row][cols nc*16+kg*4..+3] = acc + c1/4, bf16-packed into LDS
  // (8 KiB/wave), then full-row streams (each instr = 2 rows x 512 B).
  const fx4* c1_4 = (const fx4*)c1;
#pragma unroll
  for (int nc = 0; nc < 16; ++nc) {
    fx4 cv = c1_4[nc * 4 + kg];
    unsigned lo = (unsigned)f2bf(acc[nc][0] + 0.25f * cv.x)
                | ((unsigned)f2bf(acc[nc][1] + 0.25f * cv.y) << 16);
    unsigned hi = (unsigned)f2bf(acc[nc][2] + 0.25f * cv.z)
                | ((unsigned)f2bf(acc[nc][3] + 0.25f * cv.w) << 16);
    unsigned sb = (unsigned)(wv * 8192 + row * 512 + nc * 32 + kg * 8)
                ^ (unsigned)((row & 7) << 4);
    *(uint2*)(lds + sb) = make_uint2(lo, hi);
  }
#pragma unroll
  for (int i = 0; i < 8; ++i) {
    int srow  = 2 * i + (lane >> 5);
    int chunk = lane & 31;
    unsigned sb = (unsigned)(wv * 8192 + srow * 512 + chunk * 16)
                ^ (unsigned)((srow & 7) << 4);
    uint4 v = *(const uint4*)(lds + sb);
    *(uint4*)(Yp + (size_t)(rb + wv * 16 + srow) * 256 + chunk * 8) = v;
  }
}

// ---------- K23: half-staged W2-in-LDS + MLP-batched gather (R15, 139 us) ----------
// grid 1800, block 512 (8 waves, 16 rows/wave = 128 rows/block). LDS 64 KiB,
// 2 blocks/CU (unified-RF ceiling: acc 64 + hfr 32 + misc ~ 124 regs/wave ->
// 16 waves/CU max; R12's 32-wave attempt spilled). Gather loads issued in
// 16-deep batches pinned by sched_barrier(0) -> 16 concurrent L3/HBM round
// trips per wave. R16's kernel-split test proved this fused form already
// overlaps gather latency with W2 staging + MFMA better than specialization.
__global__ __launch_bounds__(512, 2) void k23_recv(
    const unsigned short* __restrict__ Yp, const int* __restrict__ edge_src,
    const unsigned short* __restrict__ W2f, const float* __restrict__ b2f,
    float* __restrict__ out) {
  __shared__ char lds[65536];              // 64 KiB

  const int tid  = threadIdx.x;
  const int lane = tid & 63;
  const int wv   = tid >> 6;               // 0..7
  const int row  = lane & 15;              // receiver row within wave tile
  const int kg   = lane >> 4;              // 0..3: k-group within fragment

  const int blk = blockIdx.x;
  const int b   = blk / 900;               // batch
  const int rr0 = (blk % 900) * 128;       // receiver row base within batch
  const unsigned short* yb = Yp + (size_t)b * NSND * 256;

  // phase A: reg-direct gather of this lane's H fragments, in 2 batches of 16
  // loads (4 ks x 4 sources, 64 dest VGPRs) pinned by sched_barrier.
  int4 s = ((const int4*)edge_src)[rr0 + wv * 16 + row];
  const unsigned short* y0 = yb + (size_t)s.x * 256 + kg * 8;
  const unsigned short* y1 = yb + (size_t)s.y * 256 + kg * 8;
  const unsigned short* y2 = yb + (size_t)s.z * 256 + kg * 8;
  const unsigned short* y3 = yb + (size_t)s.w * 256 + kg * 8;

  bx8 hfr[8];
#pragma unroll
  for (int g = 0; g < 2; ++g) {
    bx8 d[4][4];
#pragma unroll
    for (int t = 0; t < 4; ++t) {
      int ks = g * 4 + t;
      d[t][0] = *(const bx8*)(y0 + ks * 32);
      d[t][1] = *(const bx8*)(y1 + ks * 32);
      d[t][2] = *(const bx8*)(y2 + ks * 32);
      d[t][3] = *(const bx8*)(y3 + ks * 32);
    }
    __builtin_amdgcn_sched_barrier(0);     // loads may not sink past this
#pragma unroll
    for (int t = 0; t < 4; ++t) {
      int ks = g * 4 + t;
      unsigned p[4];
#pragma unroll
      for (int h = 0; h < 4; ++h) {
        float v0 = (float)d[t][0][2*h] + (float)d[t][1][2*h] + (float)d[t][2][2*h] + (float)d[t][3][2*h];
        float v1 = (float)d[t][0][2*h+1] + (float)d[t][1][2*h+1] + (float)d[t][2][2*h+1] + (float)d[t][3][2*h+1];
        float h0 = v0 / (1.f + __expf(-v0));   // silu
        float h1 = v1 / (1.f + __expf(-v1));
        p[h] = (unsigned)f2bf(h0) | ((unsigned)f2bf(h1) << 16);
      }
      uint4 pu = make_uint4(p[0], p[1], p[2], p[3]);
      hfr[ks] = *(bx8*)&pu;
    }
  }

  // phase B0: stage W2 half 0 (nc 0-7, first 64 KiB) -- wave wv copies 8 KiB
#pragma unroll
  for (int i = 0; i < 8; ++i) {
    unsigned off = (unsigned)(wv * 8192 + i * 1024 + lane * 16);
    uint4 v = *(const uint4*)((const char*)W2f + off);
    *(uint4*)(lds + off) = v;
  }
  __syncthreads();

  fx4 acc[16];
#pragma unroll
  for (int nc = 0; nc < 16; ++nc) acc[nc] = (fx4){0.f, 0.f, 0.f, 0.f};

  // phase C0: MFMA pass over nc 0..7 (W from LDS, H from registers)
#pragma unroll
  for (int ks = 0; ks < 8; ++ks) {
#pragma unroll
    for (int q = 0; q < 8; ++q) {
      bx8 wfr = *(const bx8*)(lds + (unsigned)((q * 8 + ks) * 1024 + lane * 16));
      acc[q] = __builtin_amdgcn_mfma_f32_16x16x32_bf16(wfr, hfr[ks], acc[q], 0, 0, 0);
    }
  }
  __syncthreads();   // half-0 reads complete

  // phase B1: stage W2 half 1 (nc 8-15)
#pragma unroll
  for (int i = 0; i < 8; ++i) {
    unsigned off = (unsigned)(wv * 8192 + i * 1024 + lane * 16);
    uint4 v = *(const uint4*)((const char*)W2f + 65536 + off);
    *(uint4*)(lds + off) = v;
  }
  __syncthreads();

  // phase C1: MFMA pass over nc 8..15
#pragma unroll
  for (int ks = 0; ks < 8; ++ks) {
#pragma unroll
    for (int q = 0; q < 8; ++q) {
      bx8 wfr = *(const bx8*)(lds + (unsigned)((q * 8 + ks) * 1024 + lane * 16));
      acc[8 + q] = __builtin_amdgcn_mfma_f32_16x16x32_bf16(wfr, hfr[ks], acc[8 + q], 0, 0, 0);
    }
  }
  __syncthreads();   // half-1 reads complete before epilogue overwrites LDS

  // phase D: staged epilogue (validated R7/R8 pattern), two half-col passes;
  // per wave 8 KiB slice, per-store-instr = contiguous aligned 1 KiB.
  const fx4* b2f4 = (const fx4*)b2f;
  const size_t orow0 = ((size_t)b * NRECV + rr0 + wv * 16) * 256;
#pragma unroll
  for (int p = 0; p < 2; ++p) {
#pragma unroll
    for (int q = 0; q < 8; ++q) {
      int nc = p * 8 + q;
      fx4 o = acc[nc] + b2f4[nc * 4 + kg];
      unsigned sb = (unsigned)(wv * 8192 + row * 512 + q * 64 + kg * 16)
                  ^ (unsigned)((row & 7) << 4);
      *(fx4*)(lds + sb) = o;
    }
#pragma unroll
    for (int i = 0; i < 8; ++i) {
      int srow  = 2 * i + (lane >> 5);     // 0..15
      int chunk = lane & 31;               // 16B chunk within 512B
      unsigned sb = (unsigned)(wv * 8192 + srow * 512 + chunk * 16)
                  ^ (unsigned)((srow & 7) << 4);
      fx4 v = *(const fx4*)(lds + sb);
      __builtin_nontemporal_store(v, (fx4*)(out + orow0 + (size_t)srow * 256 + p * 128 + chunk * 4));
    }
  }
}

// ---------- fallback (R3-validated fused kernel) if ws is too small ----------
__global__ __launch_bounds__(256, 4) void heal_fused(
    const float* __restrict__ x, const int* __restrict__ edge_src,
    const float* __restrict__ c1, const unsigned short* __restrict__ W1f,
    const unsigned short* __restrict__ W2f, const float* __restrict__ b2f,
    float* __restrict__ out) {
  __shared__ char lds[64 * 512];
  const int lane = threadIdx.x & 63;
  const int wv   = threadIdx.x >> 6;
  const int blk = blockIdx.x;
  const int b   = blk / 1800;
  const int r0  = (blk % 1800) * 64;
  const float* xb = x + (size_t)b * NSND * 256;
#pragma unroll 4
  for (int i = 0; i < 16; ++i) {
    int row = wv * 16 + i;
    int r   = r0 + row;
    int4 s  = *(const int4*)(edge_src + 4 * (size_t)r);
    float4 a0 = *((const float4*)(xb + (size_t)s.x * 256) + lane);
    float4 a1 = *((const float4*)(xb + (size_t)s.y * 256) + lane);
    float4 a2 = *((const float4*)(xb + (size_t)s.z * 256) + lane);
    float4 a3 = *((const float4*)(xb + (size_t)s.w * 256) + lane);
    float v0 = a0.x + a1.x + a2.x + a3.x;
    float v1 = a0.y + a1.y + a2.y + a3.y;
    float v2 = a0.z + a1.z + a2.z + a3.z;
    float v3 = a0.w + a1.w + a2.w + a3.w;
    unsigned lo = (unsigned)f2bf(v0) | ((unsigned)f2bf(v1) << 16);
    unsigned hi = (unsigned)f2bf(v2) | ((unsigned)f2bf(v3) << 16);
    unsigned byte = (unsigned)(row * 512 + lane * 8) ^ (unsigned)((row & 7) << 4);
    *(uint2*)(lds + byte) = make_uint2(lo, hi);
  }
  fx4 acc[16];
#pragma unroll
  for (int nc = 0; nc < 16; ++nc) acc[nc] = (fx4){0.f, 0.f, 0.f, 0.f};
  const bx8* W1v = (const bx8*)W1f;
  const int arow = wv * 16 + (lane & 15);
  const unsigned aswz = (unsigned)((arow & 7) << 4);
  const unsigned alin = (unsigned)(arow * 512 + (lane >> 4) * 16);
#pragma unroll
  for (int ks = 0; ks < 8; ++ks) {
    bx8 afr = *(const bx8*)(lds + ((alin + ks * 64) ^ aswz));
#pragma unroll
    for (int nc = 0; nc < 16; ++nc) {
      bx8 bfr = W1v[(nc * 8 + ks) * 64 + lane];
      acc[nc] = __builtin_amdgcn_mfma_f32_16x16x32_bf16(afr, bfr, acc[nc], 0, 0, 0);
    }
  }
  float c1v[16];
#pragma unroll
  for (int nc = 0; nc < 16; ++nc) c1v[nc] = c1[nc * 16 + (lane & 15)];
#pragma unroll
  for (int nc = 0; nc < 16; ++nc) {
    int hcol = nc * 16 + (lane & 15);
#pragma unroll
    for (int j = 0; j < 4; ++j) {
      float v = acc[nc][j] + c1v[nc];
      float h = v / (1.f + __expf(-v));
      int hrow = wv * 16 + (lane >> 4) * 4 + j;
      unsigned hb = (unsigned)(hrow * 512 + hcol * 2) ^ (unsigned)((hrow & 7) << 4);
      *(unsigned short*)(lds + hb) = f2bf(h);
    }
  }
#pragma unroll
  for (int nc = 0; nc < 16; ++nc) acc[nc] = (fx4){0.f, 0.f, 0.f, 0.f};
  const bx8* W2v = (const bx8*)W2f;
#pragma unroll
  for (int ks = 0; ks < 8; ++ks) {
    bx8 afr = *(const bx8*)(lds + ((alin + ks * 64) ^ aswz));
#pragma unroll
    for (int nc = 0; nc < 16; ++nc) {
      bx8 bfr = W2v[(nc * 8 + ks) * 64 + lane];
      acc[nc] = __builtin_amdgcn_mfma_f32_16x16x32_bf16(afr, bfr, acc[nc], 0, 0, 0);
    }
  }
  size_t obase = ((size_t)b * NRECV + r0) * 256;
#pragma unroll
  for (int nc = 0; nc < 16; ++nc) {
    int col = nc * 16 + (lane & 15);
    float bias = b2f[col];
#pragma unroll
    for (int j = 0; j < 4; ++j) {
      int row = wv * 16 + (lane >> 4) * 4 + j;
      out[obase + (size_t)row * 256 + col] = acc[nc][j] + bias;
    }
  }
}

extern "C" void kernel_launch(void* const* d_in, const int* in_sizes, int n_in,
                              void* d_out, int out_size, void* d_ws, size_t ws_size,
                              hipStream_t stream) {
  const float* x    = (const float*)d_in[0];
  const float* w1e  = (const float*)d_in[2];
  const float* b1e  = (const float*)d_in[3];
  const float* w2e  = (const float*)d_in[4];
  const float* b2e  = (const float*)d_in[5];
  const float* w1f  = (const float*)d_in[6];
  const float* b1f  = (const float*)d_in[7];
  const float* w2f  = (const float*)d_in[8];
  const float* b2f  = (const float*)d_in[9];
  const int* edge_src = (const int*)d_in[10];
  float* out = (float*)d_out;

  char* ws = (char*)d_ws;
  float* c1            = (float*)ws;                       // @0, 1 KiB
  unsigned short* W1f  = (unsigned short*)(ws + 4096);     // 128 KiB
  unsigned short* W2f  = (unsigned short*)(ws + 4096 + 131072);
  unsigned short* Yp   = (unsigned short*)(ws + 1048576);  // 48 MiB bf16 Y'
  const size_t need = 1048576 + (size_t)NSROWS * 256 * 2;

  hipLaunchKernelGGL(prep_c1, dim3(1), dim3(256), 0, stream, w1e, b1e, w2e, b2e, w1f, b1f, c1);
  hipLaunchKernelGGL(prep_w, dim3(32), dim3(256), 0, stream, w1f, w2f, W1f, W2f);
  if (ws_size >= need) {
    hipLaunchKernelGGL(k1_senders, dim3(NSROWS / 128), dim3(512), 0, stream, x, c1, W1f, Yp);
    hipLaunchKernelGGL(k23_recv, dim3(NRROWS / 128), dim3(512), 0, stream,
                       Yp, edge_src, W2f, b2f, out);
  } else {
    hipLaunchKernelGGL(heal_fused, dim3(NRROWS / 64), dim3(256), 0, stream,
                       x, edge_src, c1, W1f, W2f, b2f, out);
  }
}